// Round 3
// baseline (37424.762 us; speedup 1.0000x reference)
//
#include <hip/hip_runtime.h>

// ---------------- problem constants ----------------
constexpr int N  = 325;   // nodes
constexpr int B  = 64;    // batch
constexpr int T  = 12;    // encoder steps
constexpr int HZ = 12;    // decoder horizon
constexpr int U  = 64;    // rnn units
constexpr int BN = B * N; // 20800 rows
constexpr int FC = 16;    // feature chunk per diffusion block

// ---------------- kernels ----------------

__global__ void zero_kernel(float* __restrict__ p, int n) {
    int i = blockIdx.x * blockDim.x + threadIdx.x;
    const int stride = gridDim.x * blockDim.x;
    for (; i < n; i += stride) p[i] = 0.f;
}

// One block = (batch b, feature chunk fc0..fc0+15). Holds all N nodes of its
// feature slice in LDS so both Chebyshev diffusion steps run without grid sync.
// Writes z0 (= concat input), z1 = S@z0, z2 = 2*S@z1 - z0.
template<bool RMUL>
__global__ __launch_bounds__(256)
void diff_kernel(const float* __restrict__ S, const float* __restrict__ x,
                 const float* __restrict__ h, const float* __restrict__ ru,
                 float* __restrict__ z0, float* __restrict__ z1,
                 float* __restrict__ z2, int din, int F)
{
    __shared__ __align__(16) float s0[N * FC];
    __shared__ __align__(16) float s1[N * FC];
    const int b   = blockIdx.y;
    const int fc0 = blockIdx.x * FC;
    const int tid = threadIdx.x;

    // phase 1: concat(x, h or r*h) slice -> LDS, also materialize z0
    for (int idx = tid; idx < N * FC; idx += 256) {
        const int n  = idx / FC;
        const int f  = idx - n * FC;
        const int gf = fc0 + f;
        float v = 0.f;
        if (gf < F) {
            const int row = b * N + n;
            if (gf < din) {
                v = x[row * din + gf];
            } else {
                v = h[row * U + (gf - din)];
                if (RMUL) v *= ru[row * 128 + (gf - din)];  // r = ru[:, :64]
            }
            z0[row * F + gf] = v;
        }
        s0[idx] = v;
    }
    __syncthreads();

    const int fg = (tid & 3) * 4;  // feature sub-offset {0,4,8,12}
    const int mi = tid >> 2;       // 0..63 output rows in parallel

    // phase 2: s1 = S @ s0
    for (int pass = 0; pass < 6; ++pass) {
        const int m = pass * 64 + mi;
        if (m < N) {
            const float* __restrict__ Srow = S + m * N;
            float a0 = 0.f, a1 = 0.f, a2 = 0.f, a3 = 0.f;
            #pragma unroll 4
            for (int n = 0; n < N; ++n) {
                const float s = Srow[n];
                const float4 v = *(const float4*)&s0[n * FC + fg];
                a0 += s * v.x; a1 += s * v.y; a2 += s * v.z; a3 += s * v.w;
            }
            *(float4*)&s1[m * FC + fg] = make_float4(a0, a1, a2, a3);
            const int row = b * N + m;
            float vals[4] = {a0, a1, a2, a3};
            #pragma unroll
            for (int j = 0; j < 4; ++j) {
                const int gf = fc0 + fg + j;
                if (gf < F) z1[row * F + gf] = vals[j];
            }
        }
    }
    __syncthreads();

    // phase 3: z2 = 2 * S @ s1 - s0
    for (int pass = 0; pass < 6; ++pass) {
        const int m = pass * 64 + mi;
        if (m < N) {
            const float* __restrict__ Srow = S + m * N;
            float a0 = 0.f, a1 = 0.f, a2 = 0.f, a3 = 0.f;
            #pragma unroll 4
            for (int n = 0; n < N; ++n) {
                const float s = Srow[n];
                const float4 v = *(const float4*)&s1[n * FC + fg];
                a0 += s * v.x; a1 += s * v.y; a2 += s * v.z; a3 += s * v.w;
            }
            const int row = b * N + m;
            float vals[4] = {a0, a1, a2, a3};
            #pragma unroll
            for (int j = 0; j < 4; ++j) {
                const int gf = fc0 + fg + j;
                if (gf < F)
                    z2[row * F + gf] = 2.f * vals[j] - s0[m * FC + fg + j];
            }
        }
    }
}

// ru = sigmoid([z0|z1|z2] @ W + b), O = 128. 16 rows per block.
__global__ __launch_bounds__(256)
void dense_gate(const float* __restrict__ z0, const float* __restrict__ z1,
                const float* __restrict__ z2, const float* __restrict__ W,
                const float* __restrict__ bias, float* __restrict__ ru,
                int F, int K3)
{
    __shared__ float Zs[16 * 384];
    const int tid  = threadIdx.x;
    const int row0 = blockIdx.x * 16;

    for (int idx = tid; idx < 16 * K3; idx += 256) {
        const int r = idx / K3;
        const int k = idx - r * K3;
        const float* __restrict__ src;
        int kk;
        if (k < F)          { src = z0; kk = k; }
        else if (k < 2 * F) { src = z1; kk = k - F; }
        else                { src = z2; kk = k - 2 * F; }
        Zs[r * K3 + k] = src[(row0 + r) * F + kk];
    }
    __syncthreads();

    const int r  = tid >> 4;         // 0..15
    const int o0 = (tid & 15) * 8;   // 0..120
    float acc[8];
    #pragma unroll
    for (int j = 0; j < 8; ++j) acc[j] = bias[o0 + j];
    const float* __restrict__ zr = &Zs[r * K3];
    for (int k = 0; k < K3; ++k) {
        const float a = zr[k];
        const float4 w0 = *(const float4*)&W[k * 128 + o0];
        const float4 w1 = *(const float4*)&W[k * 128 + o0 + 4];
        acc[0] += a * w0.x; acc[1] += a * w0.y; acc[2] += a * w0.z; acc[3] += a * w0.w;
        acc[4] += a * w1.x; acc[5] += a * w1.y; acc[6] += a * w1.z; acc[7] += a * w1.w;
    }
    const int row = row0 + r;
    #pragma unroll
    for (int j = 0; j < 8; ++j)
        ru[row * 128 + o0 + j] = 1.f / (1.f + __expf(-acc[j]));
}

// c = tanh([z0|z1|z2] @ W + b), O = 64; fused GRU update h = u*h + (1-u)*c.
__global__ __launch_bounds__(256)
void dense_cand(const float* __restrict__ z0, const float* __restrict__ z1,
                const float* __restrict__ z2, const float* __restrict__ W,
                const float* __restrict__ bias, const float* __restrict__ ru,
                float* __restrict__ h, int F, int K3)
{
    __shared__ float Zs[16 * 384];
    const int tid  = threadIdx.x;
    const int row0 = blockIdx.x * 16;

    for (int idx = tid; idx < 16 * K3; idx += 256) {
        const int r = idx / K3;
        const int k = idx - r * K3;
        const float* __restrict__ src;
        int kk;
        if (k < F)          { src = z0; kk = k; }
        else if (k < 2 * F) { src = z1; kk = k - F; }
        else                { src = z2; kk = k - 2 * F; }
        Zs[r * K3 + k] = src[(row0 + r) * F + kk];
    }
    __syncthreads();

    const int r  = tid >> 4;         // 0..15
    const int o0 = (tid & 15) * 4;   // 0..60
    float acc[4];
    #pragma unroll
    for (int j = 0; j < 4; ++j) acc[j] = bias[o0 + j];
    const float* __restrict__ zr = &Zs[r * K3];
    for (int k = 0; k < K3; ++k) {
        const float a = zr[k];
        const float4 w = *(const float4*)&W[k * 64 + o0];
        acc[0] += a * w.x; acc[1] += a * w.y; acc[2] += a * w.z; acc[3] += a * w.w;
    }
    const int row = row0 + r;
    #pragma unroll
    for (int j = 0; j < 4; ++j) {
        const float c  = tanhf(acc[j]);
        const float u  = ru[row * 128 + 64 + o0 + j];   // u = ru[:, 64:]
        const float hv = h[row * 64 + o0 + j];
        h[row * 64 + o0 + j] = u * hv + (1.f - u) * c;
    }
}

// out[row] = h[row,:] . proj_W + proj_b ; also feeds next decoder input.
__global__ __launch_bounds__(256)
void proj_kernel(const float* __restrict__ h, const float* __restrict__ pW,
                 const float* __restrict__ pb, float* __restrict__ out,
                 float* __restrict__ dec_in)
{
    const int row = blockIdx.x * 256 + threadIdx.x;
    if (row >= BN) return;
    float acc = pb[0];
    const float4* __restrict__ hv = (const float4*)(h + row * 64);
    #pragma unroll
    for (int k4 = 0; k4 < 16; ++k4) {
        const float4 v = hv[k4];
        acc += v.x * pW[k4 * 4 + 0] + v.y * pW[k4 * 4 + 1]
             + v.z * pW[k4 * 4 + 2] + v.w * pW[k4 * 4 + 3];
    }
    out[row]    = acc;
    dec_in[row] = acc;
}

// ---------------- host launcher ----------------

extern "C" void kernel_launch(void* const* d_in, const int* in_sizes, int n_in,
                              void* d_out, int out_size, void* d_ws, size_t ws_size,
                              hipStream_t stream)
{
    const float* inputs = (const float*)d_in[0];
    const float* S      = (const float*)d_in[1];
    // [layer][gate_W, gate_b, cand_W, cand_b], layers: enc0, enc1, dec0, dec1
    const float* Wt[4][4];
    for (int l = 0; l < 4; ++l)
        for (int j = 0; j < 4; ++j)
            Wt[l][j] = (const float*)d_in[2 + l * 4 + j];
    const float* pW = (const float*)d_in[18];
    const float* pb = (const float*)d_in[19];
    float* out = (float*)d_out;

    // workspace layout (floats): h0, h1 (carried enc->dec!), dec_in, z0..z2, ru
    float* ws     = (float*)d_ws;
    float* h0     = ws;                  // layer-0 hidden (enc, then dec continues)
    float* h1     = h0 + BN * U;         // layer-1 hidden
    float* dec_in = h1 + BN * U;
    float* z0     = dec_in + BN;
    float* z1     = z0 + BN * 128;
    float* z2     = z1 + BN * 128;
    float* ru     = z2 + BN * 128;

    // zero h-states + decoder GO input (ws is poisoned each call)
    zero_kernel<<<1024, 256, 0, stream>>>(h0, 2 * BN * U + BN);

    auto cell = [&](const float* x, int din, float* h, const float* const* wl) {
        const int F = din + U;
        dim3 g1((F + FC - 1) / FC, B);
        diff_kernel<false><<<g1, 256, 0, stream>>>(S, x, h, nullptr, z0, z1, z2, din, F);
        dense_gate<<<BN / 16, 256, 0, stream>>>(z0, z1, z2, wl[0], wl[1], ru, F, 3 * F);
        diff_kernel<true><<<g1, 256, 0, stream>>>(S, x, h, ru, z0, z1, z2, din, F);
        dense_cand<<<BN / 16, 256, 0, stream>>>(z0, z1, z2, wl[2], wl[3], ru, h, F, 3 * F);
    };

    for (int t = 0; t < T; ++t) {
        cell(inputs + (size_t)t * BN * 2, 2, h0, Wt[0]);
        cell(h0, 64, h1, Wt[1]);
    }
    // decoder continues from the encoder's final hidden states (reference:
    // scan carry starts at (start, h_l0, h_l1)) — h0/h1 updated in place.
    for (int hz = 0; hz < HZ; ++hz) {
        cell(dec_in, 1, h0, Wt[2]);
        cell(h0, 64, h1, Wt[3]);
        proj_kernel<<<(BN + 255) / 256, 256, 0, stream>>>(h1, pW, pb,
                                                          out + (size_t)hz * BN, dec_in);
    }
}

// Round 4
// 11018.126 us; speedup vs baseline: 3.3967x; 3.3967x over previous
//
#include <hip/hip_runtime.h>

// ---------------- problem constants ----------------
constexpr int N  = 325;   // nodes
constexpr int B  = 64;    // batch
constexpr int T  = 12;    // encoder steps
constexpr int HZ = 12;    // decoder horizon
constexpr int U  = 64;    // rnn units
constexpr int BN = B * N; // 20800 rows
constexpr int FC = 16;    // feature chunk per diffusion block
constexpr int ELLW = 352; // ELL capacity >= N, can never overflow

// ---------------- kernels ----------------

__global__ void zero_kernel(float* __restrict__ p, int n) {
    int i = blockIdx.x * blockDim.x + threadIdx.x;
    const int stride = gridDim.x * blockDim.x;
    for (; i < n; i += stride) p[i] = 0.f;
}

// Build ELL (column-major, interleaved val/col) from dense S. One wave per row.
// S is ~10% dense (support = -Dinv A Dinv keeps A's sparsity) -> ~33 nnz/row.
__global__ __launch_bounds__(64)
void ell_build(const float* __restrict__ S, float2* __restrict__ ellcv,
               int* __restrict__ nnz)
{
    const int m    = blockIdx.x;
    const int lane = threadIdx.x;
    const float* __restrict__ row = S + m * N;
    int count = 0;
    for (int base = 0; base < N; base += 64) {
        const int n = base + lane;
        const float v = (n < N) ? row[n] : 0.f;
        const unsigned long long mask = __ballot(v != 0.f);
        const int pre = __popcll(mask & ((1ull << lane) - 1ull));
        if (v != 0.f) {
            const int pos = count + pre;   // pos < N <= ELLW always
            ellcv[pos * N + m] = make_float2(v, __int_as_float(n));
        }
        count += __popcll(mask);
    }
    if (lane == 0) nnz[m] = count;
}

// One block = (batch b, feature chunk fc0..fc0+15). Holds all N nodes of its
// feature slice in LDS; both Chebyshev steps use the SPARSE S (ELL).
// Writes z0 (= concat input), z1 = S@z0, z2 = 2*S@z1 - z0.
template<bool RMUL>
__global__ __launch_bounds__(256)
void diff_kernel(const float2* __restrict__ ellcv, const int* __restrict__ nnz,
                 const float* __restrict__ x, const float* __restrict__ h,
                 const float* __restrict__ ru,
                 float* __restrict__ z0, float* __restrict__ z1,
                 float* __restrict__ z2, int din, int F)
{
    __shared__ __align__(16) float s0[N * FC];
    __shared__ __align__(16) float s1[N * FC];
    const int b   = blockIdx.y;
    const int fc0 = blockIdx.x * FC;
    const int tid = threadIdx.x;

    // phase 1: concat(x, h or r*h) slice -> LDS, also materialize z0
    for (int idx = tid; idx < N * FC; idx += 256) {
        const int n  = idx / FC;
        const int f  = idx - n * FC;
        const int gf = fc0 + f;
        float v = 0.f;
        if (gf < F) {
            const int row = b * N + n;
            if (gf < din) {
                v = x[row * din + gf];
            } else {
                v = h[row * U + (gf - din)];
                if (RMUL) v *= ru[row * 128 + (gf - din)];  // r = ru[:, :64]
            }
            z0[row * F + gf] = v;
        }
        s0[idx] = v;
    }
    __syncthreads();

    const int fg = (tid & 3) * 4;  // feature sub-offset {0,4,8,12}
    const int mi = tid >> 2;       // 0..63 output rows in parallel

    // phase 2: s1 = S @ s0 (sparse)
    for (int pass = 0; pass < 6; ++pass) {
        const int m = pass * 64 + mi;
        if (m < N) {
            const int cnt = nnz[m];
            float a0 = 0.f, a1 = 0.f, a2 = 0.f, a3 = 0.f;
            #pragma unroll 4
            for (int j = 0; j < cnt; ++j) {
                const float2 cv = ellcv[j * N + m];
                const int col = __float_as_int(cv.y);
                const float4 v = *(const float4*)&s0[col * FC + fg];
                a0 += cv.x * v.x; a1 += cv.x * v.y; a2 += cv.x * v.z; a3 += cv.x * v.w;
            }
            *(float4*)&s1[m * FC + fg] = make_float4(a0, a1, a2, a3);
            const int row = b * N + m;
            float vals[4] = {a0, a1, a2, a3};
            #pragma unroll
            for (int j = 0; j < 4; ++j) {
                const int gf = fc0 + fg + j;
                if (gf < F) z1[row * F + gf] = vals[j];
            }
        }
    }
    __syncthreads();

    // phase 3: z2 = 2 * S @ s1 - s0 (sparse)
    for (int pass = 0; pass < 6; ++pass) {
        const int m = pass * 64 + mi;
        if (m < N) {
            const int cnt = nnz[m];
            float a0 = 0.f, a1 = 0.f, a2 = 0.f, a3 = 0.f;
            #pragma unroll 4
            for (int j = 0; j < cnt; ++j) {
                const float2 cv = ellcv[j * N + m];
                const int col = __float_as_int(cv.y);
                const float4 v = *(const float4*)&s1[col * FC + fg];
                a0 += cv.x * v.x; a1 += cv.x * v.y; a2 += cv.x * v.z; a3 += cv.x * v.w;
            }
            const int row = b * N + m;
            float vals[4] = {a0, a1, a2, a3};
            #pragma unroll
            for (int j = 0; j < 4; ++j) {
                const int gf = fc0 + fg + j;
                if (gf < F)
                    z2[row * F + gf] = 2.f * vals[j] - s0[m * FC + fg + j];
            }
        }
    }
}

// ru = sigmoid([z0|z1|z2] @ W + b), O = 128. 16 rows per block.
// Zs padded to stride K3+8 (!= 0 mod 32) -> r-groups on distinct banks.
__global__ __launch_bounds__(256)
void dense_gate(const float* __restrict__ z0, const float* __restrict__ z1,
                const float* __restrict__ z2, const float* __restrict__ W,
                const float* __restrict__ bias, float* __restrict__ ru,
                int F, int K3)
{
    __shared__ float Zs[16 * 392];
    const int K3p  = K3 + 8;
    const int tid  = threadIdx.x;
    const int row0 = blockIdx.x * 16;

    for (int idx = tid; idx < 16 * K3; idx += 256) {
        const int r = idx / K3;
        const int k = idx - r * K3;
        const float* __restrict__ src;
        int kk;
        if (k < F)          { src = z0; kk = k; }
        else if (k < 2 * F) { src = z1; kk = k - F; }
        else                { src = z2; kk = k - 2 * F; }
        Zs[r * K3p + k] = src[(row0 + r) * F + kk];
    }
    __syncthreads();

    const int r  = tid >> 4;         // 0..15
    const int o0 = (tid & 15) * 8;   // 0..120
    float acc[8];
    #pragma unroll
    for (int j = 0; j < 8; ++j) acc[j] = bias[o0 + j];
    const float* __restrict__ zr = &Zs[r * K3p];
    for (int k = 0; k < K3; ++k) {
        const float a = zr[k];
        const float4 w0 = *(const float4*)&W[k * 128 + o0];
        const float4 w1 = *(const float4*)&W[k * 128 + o0 + 4];
        acc[0] += a * w0.x; acc[1] += a * w0.y; acc[2] += a * w0.z; acc[3] += a * w0.w;
        acc[4] += a * w1.x; acc[5] += a * w1.y; acc[6] += a * w1.z; acc[7] += a * w1.w;
    }
    const int row = row0 + r;
    #pragma unroll
    for (int j = 0; j < 8; ++j)
        ru[row * 128 + o0 + j] = 1.f / (1.f + __expf(-acc[j]));
}

// c = tanh([z0|z1|z2] @ W + b), O = 64; fused GRU update h = u*h + (1-u)*c.
__global__ __launch_bounds__(256)
void dense_cand(const float* __restrict__ z0, const float* __restrict__ z1,
                const float* __restrict__ z2, const float* __restrict__ W,
                const float* __restrict__ bias, const float* __restrict__ ru,
                float* __restrict__ h, int F, int K3)
{
    __shared__ float Zs[16 * 392];
    const int K3p  = K3 + 8;
    const int tid  = threadIdx.x;
    const int row0 = blockIdx.x * 16;

    for (int idx = tid; idx < 16 * K3; idx += 256) {
        const int r = idx / K3;
        const int k = idx - r * K3;
        const float* __restrict__ src;
        int kk;
        if (k < F)          { src = z0; kk = k; }
        else if (k < 2 * F) { src = z1; kk = k - F; }
        else                { src = z2; kk = k - 2 * F; }
        Zs[r * K3p + k] = src[(row0 + r) * F + kk];
    }
    __syncthreads();

    const int r  = tid >> 4;         // 0..15
    const int o0 = (tid & 15) * 4;   // 0..60
    float acc[4];
    #pragma unroll
    for (int j = 0; j < 4; ++j) acc[j] = bias[o0 + j];
    const float* __restrict__ zr = &Zs[r * K3p];
    for (int k = 0; k < K3; ++k) {
        const float a = zr[k];
        const float4 w = *(const float4*)&W[k * 64 + o0];
        acc[0] += a * w.x; acc[1] += a * w.y; acc[2] += a * w.z; acc[3] += a * w.w;
    }
    const int row = row0 + r;
    #pragma unroll
    for (int j = 0; j < 4; ++j) {
        const float c  = tanhf(acc[j]);
        const float u  = ru[row * 128 + 64 + o0 + j];   // u = ru[:, 64:]
        const float hv = h[row * 64 + o0 + j];
        h[row * 64 + o0 + j] = u * hv + (1.f - u) * c;
    }
}

// out[row] = h[row,:] . proj_W + proj_b ; also feeds next decoder input.
__global__ __launch_bounds__(256)
void proj_kernel(const float* __restrict__ h, const float* __restrict__ pW,
                 const float* __restrict__ pb, float* __restrict__ out,
                 float* __restrict__ dec_in)
{
    const int row = blockIdx.x * 256 + threadIdx.x;
    if (row >= BN) return;
    float acc = pb[0];
    const float4* __restrict__ hv = (const float4*)(h + row * 64);
    #pragma unroll
    for (int k4 = 0; k4 < 16; ++k4) {
        const float4 v = hv[k4];
        acc += v.x * pW[k4 * 4 + 0] + v.y * pW[k4 * 4 + 1]
             + v.z * pW[k4 * 4 + 2] + v.w * pW[k4 * 4 + 3];
    }
    out[row]    = acc;
    dec_in[row] = acc;
}

// ---------------- host launcher ----------------

extern "C" void kernel_launch(void* const* d_in, const int* in_sizes, int n_in,
                              void* d_out, int out_size, void* d_ws, size_t ws_size,
                              hipStream_t stream)
{
    const float* inputs = (const float*)d_in[0];
    const float* S      = (const float*)d_in[1];
    // [layer][gate_W, gate_b, cand_W, cand_b], layers: enc0, enc1, dec0, dec1
    const float* Wt[4][4];
    for (int l = 0; l < 4; ++l)
        for (int j = 0; j < 4; ++j)
            Wt[l][j] = (const float*)d_in[2 + l * 4 + j];
    const float* pW = (const float*)d_in[18];
    const float* pb = (const float*)d_in[19];
    float* out = (float*)d_out;

    // workspace layout (floats): h0, h1 (carried enc->dec!), dec_in, z0..z2,
    // ru, ELL(S). Everything re-initialized each call (ws is poisoned).
    float*  ws     = (float*)d_ws;
    float*  h0     = ws;                 // layer-0 hidden (enc, then dec)
    float*  h1     = h0 + BN * U;
    float*  dec_in = h1 + BN * U;
    float*  z0     = dec_in + BN;
    float*  z1     = z0 + BN * 128;
    float*  z2     = z1 + BN * 128;
    float*  ru     = z2 + BN * 128;
    float2* ellcv  = (float2*)(ru + BN * 128);
    int*    nnz    = (int*)(ellcv + (size_t)ELLW * N);

    zero_kernel<<<1024, 256, 0, stream>>>(h0, 2 * BN * U + BN);
    ell_build<<<N, 64, 0, stream>>>(S, ellcv, nnz);

    auto cell = [&](const float* x, int din, float* h, const float* const* wl) {
        const int F = din + U;
        dim3 g1((F + FC - 1) / FC, B);
        diff_kernel<false><<<g1, 256, 0, stream>>>(ellcv, nnz, x, h, nullptr,
                                                   z0, z1, z2, din, F);
        dense_gate<<<BN / 16, 256, 0, stream>>>(z0, z1, z2, wl[0], wl[1], ru, F, 3 * F);
        diff_kernel<true><<<g1, 256, 0, stream>>>(ellcv, nnz, x, h, ru,
                                                  z0, z1, z2, din, F);
        dense_cand<<<BN / 16, 256, 0, stream>>>(z0, z1, z2, wl[2], wl[3], ru, h, F, 3 * F);
    };

    for (int t = 0; t < T; ++t) {
        cell(inputs + (size_t)t * BN * 2, 2, h0, Wt[0]);
        cell(h0, 64, h1, Wt[1]);
    }
    // decoder continues from the encoder's final hidden states
    for (int hz = 0; hz < HZ; ++hz) {
        cell(dec_in, 1, h0, Wt[2]);
        cell(h0, 64, h1, Wt[3]);
        proj_kernel<<<(BN + 255) / 256, 256, 0, stream>>>(h1, pW, pb,
                                                          out + (size_t)hz * BN, dec_in);
    }
}

// Round 5
// 6083.449 us; speedup vs baseline: 6.1519x; 1.8112x over previous
//
#include <hip/hip_runtime.h>

// ---------------- problem constants ----------------
constexpr int N  = 325;   // nodes
constexpr int B  = 64;    // batch
constexpr int T  = 12;    // encoder steps
constexpr int HZ = 12;    // decoder horizon
constexpr int U  = 64;    // rnn units
constexpr int BN = B * N; // 20800 rows
constexpr int FC = 16;    // feature chunk per diffusion block
constexpr int ELLW = 352; // ELL capacity >= N, can never overflow

typedef __attribute__((ext_vector_type(8))) short short8;
typedef __attribute__((ext_vector_type(4))) float floatx4;

// bf16 round-to-nearest-even + hi/lo split helpers
__device__ inline unsigned short f2bf(float f) {
    unsigned u = __float_as_uint(f);
    u += 0x7fff + ((u >> 16) & 1);
    return (unsigned short)(u >> 16);
}
__device__ inline unsigned pack_hilo(float v) {
    const unsigned short hi = f2bf(v);
    const float hif = __uint_as_float(((unsigned)hi) << 16);
    const unsigned short lo = f2bf(v - hif);
    return (unsigned)hi | ((unsigned)lo << 16);
}

// ---------------- kernels ----------------

__global__ void zero_kernel(float* __restrict__ p, int n) {
    int i = blockIdx.x * blockDim.x + threadIdx.x;
    const int stride = gridDim.x * blockDim.x;
    for (; i < n; i += stride) p[i] = 0.f;
}

// Build ELL (column-major, interleaved val/col) from dense S. One wave per row.
__global__ __launch_bounds__(64)
void ell_build(const float* __restrict__ S, float2* __restrict__ ellcv,
               int* __restrict__ nnz)
{
    const int m    = blockIdx.x;
    const int lane = threadIdx.x;
    const float* __restrict__ row = S + m * N;
    int count = 0;
    for (int base = 0; base < N; base += 64) {
        const int n = base + lane;
        const float v = (n < N) ? row[n] : 0.f;
        const unsigned long long mask = __ballot(v != 0.f);
        const int pre = __popcll(mask & ((1ull << lane) - 1ull));
        if (v != 0.f) {
            const int pos = count + pre;   // pos < N <= ELLW always
            ellcv[pos * N + m] = make_float2(v, __int_as_float(n));
        }
        count += __popcll(mask);
    }
    if (lane == 0) nnz[m] = count;
}

// Pre-pack a weight matrix (K3 x Nout, row-major fp32) into MFMA B-fragment
// order, split into bf16 hi/lo. Fragment: B[k=(lane>>4)*8+j][n*16+(lane&15)],
// stored as short8 at ((kc*NT+n)*64+lane). Zero-padded to K3p.
__global__ __launch_bounds__(64)
void prepack_w(const float* __restrict__ W, short* __restrict__ Wh,
               short* __restrict__ Wl, int K3, int Nout, int NT)
{
    const int kc = blockIdx.x, n = blockIdx.y, lane = threadIdx.x;
    const int quad = lane >> 4, l15 = lane & 15;
    short8 hv, lv;
    #pragma unroll
    for (int j = 0; j < 8; ++j) {
        const int k   = kc * 32 + quad * 8 + j;
        const int col = n * 16 + l15;
        const float w = (k < K3) ? W[k * Nout + col] : 0.f;
        const unsigned short h = f2bf(w);
        const float hf = __uint_as_float(((unsigned)h) << 16);
        hv[j] = (short)h;
        lv[j] = (short)f2bf(w - hf);
    }
    const size_t off = ((size_t)(kc * NT + n) * 64 + lane);
    ((short8*)Wh)[off] = hv;
    ((short8*)Wl)[off] = lv;
}

// One block = (batch b, feature chunk). Sparse Chebyshev diffusion; writes the
// CONCATENATED z = [z0|z1|z2] as packed ushort2(bf16 hi, bf16 lo), row stride
// K3p (zero-padded to 32-multiple for the MFMA consumer).
template<bool RMUL>
__global__ __launch_bounds__(256)
void diff_kernel(const float2* __restrict__ ellcv, const int* __restrict__ nnz,
                 const float* __restrict__ x, const float* __restrict__ h,
                 const float* __restrict__ ru, unsigned* __restrict__ zcat,
                 int din, int F, int K3p)
{
    __shared__ __align__(16) float s0[N * FC];
    __shared__ __align__(16) float s1[N * FC];
    const int b   = blockIdx.y;
    const int fc0 = blockIdx.x * FC;
    const int tid = threadIdx.x;

    // phase 1: concat(x, h or r*h) slice -> LDS, also write z0 part of zcat
    for (int idx = tid; idx < N * FC; idx += 256) {
        const int n  = idx / FC;
        const int f  = idx - n * FC;
        const int gf = fc0 + f;
        float v = 0.f;
        if (gf < F) {
            const int row = b * N + n;
            if (gf < din) {
                v = x[row * din + gf];
            } else {
                v = h[row * U + (gf - din)];
                if (RMUL) v *= ru[row * 128 + (gf - din)];  // r = ru[:, :64]
            }
            zcat[(size_t)row * K3p + gf] = pack_hilo(v);
        }
        s0[idx] = v;
    }
    // zero the K-padding strip [3F, K3p) (done by chunk-0 blocks)
    if (blockIdx.x == 0) {
        const int pad = K3p - 3 * F;
        for (int idx = tid; idx < N * pad; idx += 256) {
            const int n = idx / pad;
            const int c = idx - n * pad;
            zcat[(size_t)(b * N + n) * K3p + 3 * F + c] = 0u;
        }
    }
    __syncthreads();

    const int fg = (tid & 3) * 4;  // feature sub-offset {0,4,8,12}
    const int mi = tid >> 2;       // 0..63 output rows in parallel

    // phase 2: s1 = S @ s0 (sparse)
    for (int pass = 0; pass < 6; ++pass) {
        const int m = pass * 64 + mi;
        if (m < N) {
            const int cnt = nnz[m];
            float a0 = 0.f, a1 = 0.f, a2 = 0.f, a3 = 0.f;
            #pragma unroll 4
            for (int j = 0; j < cnt; ++j) {
                const float2 cv = ellcv[j * N + m];
                const int col = __float_as_int(cv.y);
                const float4 v = *(const float4*)&s0[col * FC + fg];
                a0 += cv.x * v.x; a1 += cv.x * v.y; a2 += cv.x * v.z; a3 += cv.x * v.w;
            }
            *(float4*)&s1[m * FC + fg] = make_float4(a0, a1, a2, a3);
            const int row = b * N + m;
            float vals[4] = {a0, a1, a2, a3};
            #pragma unroll
            for (int j = 0; j < 4; ++j) {
                const int gf = fc0 + fg + j;
                if (gf < F) zcat[(size_t)row * K3p + F + gf] = pack_hilo(vals[j]);
            }
        }
    }
    __syncthreads();

    // phase 3: z2 = 2 * S @ s1 - s0 (sparse)
    for (int pass = 0; pass < 6; ++pass) {
        const int m = pass * 64 + mi;
        if (m < N) {
            const int cnt = nnz[m];
            float a0 = 0.f, a1 = 0.f, a2 = 0.f, a3 = 0.f;
            #pragma unroll 4
            for (int j = 0; j < cnt; ++j) {
                const float2 cv = ellcv[j * N + m];
                const int col = __float_as_int(cv.y);
                const float4 v = *(const float4*)&s1[col * FC + fg];
                a0 += cv.x * v.x; a1 += cv.x * v.y; a2 += cv.x * v.z; a3 += cv.x * v.w;
            }
            const int row = b * N + m;
            float vals[4] = {a0, a1, a2, a3};
            #pragma unroll
            for (int j = 0; j < 4; ++j) {
                const int gf = fc0 + fg + j;
                if (gf < F)
                    zcat[(size_t)row * K3p + 2 * F + gf] =
                        pack_hilo(2.f * vals[j] - s0[m * FC + fg + j]);
            }
        }
    }
}

// MFMA dense: ru = sigmoid(zcat @ W + b). 64 rows/block (16/wave), 128 cols.
// Split-bf16: acc += Ahi*Bhi + Ahi*Blo + Alo*Bhi (fp32-level accuracy).
__global__ __launch_bounds__(256)
void dense_gate_mfma(const unsigned* __restrict__ zcat, int K3p,
                     const short8* __restrict__ Wh, const short8* __restrict__ Wl,
                     const float* __restrict__ bias, float* __restrict__ ru)
{
    constexpr int NT = 8;
    const int tid = threadIdx.x, wave = tid >> 6, lane = tid & 63;
    const int quad = lane >> 4, l15 = lane & 15;
    const int row0 = blockIdx.x * 64 + wave * 16;

    floatx4 acc[NT];
    #pragma unroll
    for (int n = 0; n < NT; ++n) {
        const float bv = bias[n * 16 + l15];
        acc[n] = (floatx4){bv, bv, bv, bv};
    }
    const unsigned* __restrict__ zrow = zcat + (size_t)(row0 + l15) * K3p + quad * 8;
    const int KC = K3p >> 5;
    for (int kc = 0; kc < KC; ++kc) {
        const uint4* p = (const uint4*)(zrow + kc * 32);
        const uint4 u0 = p[0], u1 = p[1];
        const unsigned uu[8] = {u0.x, u0.y, u0.z, u0.w, u1.x, u1.y, u1.z, u1.w};
        short8 ahi, alo;
        #pragma unroll
        for (int j = 0; j < 8; ++j) {
            ahi[j] = (short)(uu[j] & 0xffffu);
            alo[j] = (short)(uu[j] >> 16);
        }
        const short8* __restrict__ wh = Wh + (size_t)(kc * NT) * 64 + lane;
        const short8* __restrict__ wl = Wl + (size_t)(kc * NT) * 64 + lane;
        #pragma unroll
        for (int n = 0; n < NT; ++n) {
            const short8 bh = wh[n * 64], bl = wl[n * 64];
            acc[n] = __builtin_amdgcn_mfma_f32_16x16x32_bf16(ahi, bh, acc[n], 0, 0, 0);
            acc[n] = __builtin_amdgcn_mfma_f32_16x16x32_bf16(ahi, bl, acc[n], 0, 0, 0);
            acc[n] = __builtin_amdgcn_mfma_f32_16x16x32_bf16(alo, bh, acc[n], 0, 0, 0);
        }
    }
    #pragma unroll
    for (int n = 0; n < NT; ++n) {
        const int col = n * 16 + l15;
        #pragma unroll
        for (int r = 0; r < 4; ++r) {
            const int row = row0 + quad * 4 + r;   // C/D: row=(lane>>4)*4+reg
            ru[(size_t)row * 128 + col] = 1.f / (1.f + __expf(-acc[n][r]));
        }
    }
}

// MFMA dense: c = tanh(zcat @ W + b); fused h = u*h + (1-u)*c. 64 cols.
__global__ __launch_bounds__(256)
void dense_cand_mfma(const unsigned* __restrict__ zcat, int K3p,
                     const short8* __restrict__ Wh, const short8* __restrict__ Wl,
                     const float* __restrict__ bias, const float* __restrict__ ru,
                     float* __restrict__ h)
{
    constexpr int NT = 4;
    const int tid = threadIdx.x, wave = tid >> 6, lane = tid & 63;
    const int quad = lane >> 4, l15 = lane & 15;
    const int row0 = blockIdx.x * 64 + wave * 16;

    floatx4 acc[NT];
    #pragma unroll
    for (int n = 0; n < NT; ++n) {
        const float bv = bias[n * 16 + l15];
        acc[n] = (floatx4){bv, bv, bv, bv};
    }
    const unsigned* __restrict__ zrow = zcat + (size_t)(row0 + l15) * K3p + quad * 8;
    const int KC = K3p >> 5;
    for (int kc = 0; kc < KC; ++kc) {
        const uint4* p = (const uint4*)(zrow + kc * 32);
        const uint4 u0 = p[0], u1 = p[1];
        const unsigned uu[8] = {u0.x, u0.y, u0.z, u0.w, u1.x, u1.y, u1.z, u1.w};
        short8 ahi, alo;
        #pragma unroll
        for (int j = 0; j < 8; ++j) {
            ahi[j] = (short)(uu[j] & 0xffffu);
            alo[j] = (short)(uu[j] >> 16);
        }
        const short8* __restrict__ wh = Wh + (size_t)(kc * NT) * 64 + lane;
        const short8* __restrict__ wl = Wl + (size_t)(kc * NT) * 64 + lane;
        #pragma unroll
        for (int n = 0; n < NT; ++n) {
            const short8 bh = wh[n * 64], bl = wl[n * 64];
            acc[n] = __builtin_amdgcn_mfma_f32_16x16x32_bf16(ahi, bh, acc[n], 0, 0, 0);
            acc[n] = __builtin_amdgcn_mfma_f32_16x16x32_bf16(ahi, bl, acc[n], 0, 0, 0);
            acc[n] = __builtin_amdgcn_mfma_f32_16x16x32_bf16(alo, bh, acc[n], 0, 0, 0);
        }
    }
    #pragma unroll
    for (int n = 0; n < NT; ++n) {
        const int col = n * 16 + l15;
        #pragma unroll
        for (int r = 0; r < 4; ++r) {
            const int row = row0 + quad * 4 + r;
            const float c  = tanhf(acc[n][r]);
            const float u  = ru[(size_t)row * 128 + 64 + col];  // u = ru[:, 64:]
            const float hv = h[(size_t)row * 64 + col];
            h[(size_t)row * 64 + col] = u * hv + (1.f - u) * c;
        }
    }
}

// out[row] = h[row,:] . proj_W + proj_b ; also feeds next decoder input.
__global__ __launch_bounds__(256)
void proj_kernel(const float* __restrict__ h, const float* __restrict__ pW,
                 const float* __restrict__ pb, float* __restrict__ out,
                 float* __restrict__ dec_in)
{
    const int row = blockIdx.x * 256 + threadIdx.x;
    if (row >= BN) return;
    float acc = pb[0];
    const float4* __restrict__ hv = (const float4*)(h + row * 64);
    #pragma unroll
    for (int k4 = 0; k4 < 16; ++k4) {
        const float4 v = hv[k4];
        acc += v.x * pW[k4 * 4 + 0] + v.y * pW[k4 * 4 + 1]
             + v.z * pW[k4 * 4 + 2] + v.w * pW[k4 * 4 + 3];
    }
    out[row]    = acc;
    dec_in[row] = acc;
}

// ---------------- host launcher ----------------

extern "C" void kernel_launch(void* const* d_in, const int* in_sizes, int n_in,
                              void* d_out, int out_size, void* d_ws, size_t ws_size,
                              hipStream_t stream)
{
    const float* inputs = (const float*)d_in[0];
    const float* S      = (const float*)d_in[1];
    const float* Wt[4][4];
    for (int l = 0; l < 4; ++l)
        for (int j = 0; j < 4; ++j)
            Wt[l][j] = (const float*)d_in[2 + l * 4 + j];
    const float* pW = (const float*)d_in[18];
    const float* pb = (const float*)d_in[19];
    float* out = (float*)d_out;

    // workspace layout
    float*    ws     = (float*)d_ws;
    float*    h0     = ws;                       // BN*U
    float*    h1     = h0 + BN * U;              // BN*U
    float*    dec_in = h1 + BN * U;              // BN
    float*    ru     = dec_in + BN;              // BN*128
    unsigned* zcat   = (unsigned*)(ru + BN * 128);   // BN*384 (16B aligned)
    float2*   ellcv  = (float2*)(zcat + (size_t)BN * 384);
    int*      nnz    = (int*)(ellcv + (size_t)ELLW * N);
    char*     wpbase = (char*)(nnz + ((N + 3) & ~3)) ;
    wpbase = (char*)(((uintptr_t)wpbase + 15) & ~(uintptr_t)15);

    // layer geometry: K3, K3p (pad to 32)
    const int K3s[4]  = {198, 384, 195, 384};
    const int K3ps[4] = {224, 384, 224, 384};
    short *Wgh[4], *Wgl[4], *Wch[4], *Wcl[4];
    {
        size_t off = 0;
        for (int l = 0; l < 4; ++l) {
            const size_t ge = (size_t)K3ps[l] * 128, ce = (size_t)K3ps[l] * 64;
            Wgh[l] = (short*)(wpbase + off); off += ge * 2;
            Wgl[l] = (short*)(wpbase + off); off += ge * 2;
            Wch[l] = (short*)(wpbase + off); off += ce * 2;
            Wcl[l] = (short*)(wpbase + off); off += ce * 2;
        }
    }

    zero_kernel<<<1024, 256, 0, stream>>>(h0, 2 * BN * U + BN);
    ell_build<<<N, 64, 0, stream>>>(S, ellcv, nnz);
    for (int l = 0; l < 4; ++l) {
        prepack_w<<<dim3(K3ps[l] / 32, 8), 64, 0, stream>>>(Wt[l][0], Wgh[l], Wgl[l],
                                                            K3s[l], 128, 8);
        prepack_w<<<dim3(K3ps[l] / 32, 4), 64, 0, stream>>>(Wt[l][2], Wch[l], Wcl[l],
                                                            K3s[l], 64, 4);
    }

    auto cell = [&](const float* x, int din, float* h, int l) {
        const int F = din + U, K3p = K3ps[l];
        dim3 g1((F + FC - 1) / FC, B);
        diff_kernel<false><<<g1, 256, 0, stream>>>(ellcv, nnz, x, h, nullptr,
                                                   zcat, din, F, K3p);
        dense_gate_mfma<<<BN / 64, 256, 0, stream>>>(zcat, K3p, (short8*)Wgh[l],
                                                     (short8*)Wgl[l], Wt[l][1], ru);
        diff_kernel<true><<<g1, 256, 0, stream>>>(ellcv, nnz, x, h, ru,
                                                  zcat, din, F, K3p);
        dense_cand_mfma<<<BN / 64, 256, 0, stream>>>(zcat, K3p, (short8*)Wch[l],
                                                     (short8*)Wcl[l], Wt[l][3], ru, h);
    };

    for (int t = 0; t < T; ++t) {
        cell(inputs + (size_t)t * BN * 2, 2, h0, 0);
        cell(h0, 64, h1, 1);
    }
    // decoder continues from the encoder's final hidden states (in place)
    for (int hz = 0; hz < HZ; ++hz) {
        cell(dec_in, 1, h0, 2);
        cell(h0, 64, h1, 3);
        proj_kernel<<<(BN + 255) / 256, 256, 0, stream>>>(h1, pW, pb,
                                                          out + (size_t)hz * BN, dec_in);
    }
}